// Round 1
// baseline (1004.672 us; speedup 1.0000x reference)
//
#include <hip/hip_runtime.h>
#include <hip/hip_bf16.h>
#include <cstdint>
#include <cstddef>

typedef unsigned short u16;
typedef __attribute__((ext_vector_type(8))) short bf16x8;   // MFMA A/B frag (8 bf16)
typedef __attribute__((ext_vector_type(4))) float f32x4;    // MFMA C/D frag
typedef __attribute__((ext_vector_type(4))) unsigned short u16x4;

#define B_ 4
#define N_ 8192
#define D_ 64
#define H_ 128
#define E_ 256
#define C_ 16

// ---------- helpers ----------
__device__ __forceinline__ u16 f2bf(float f) {
  unsigned u = __builtin_bit_cast(unsigned, f);
  u += 0x7fffu + ((u >> 16) & 1u);          // RNE
  return (u16)(u >> 16);
}

__device__ __forceinline__ float wave_sum(float v) {
  v += __shfl_xor(v, 32, 64); v += __shfl_xor(v, 16, 64); v += __shfl_xor(v, 8, 64);
  v += __shfl_xor(v, 4, 64);  v += __shfl_xor(v, 2, 64);  v += __shfl_xor(v, 1, 64);
  return v;
}
__device__ __forceinline__ float wave_max(float v) {
  v = fmaxf(v, __shfl_xor(v, 32, 64)); v = fmaxf(v, __shfl_xor(v, 16, 64));
  v = fmaxf(v, __shfl_xor(v, 8, 64));  v = fmaxf(v, __shfl_xor(v, 4, 64));
  v = fmaxf(v, __shfl_xor(v, 2, 64));  v = fmaxf(v, __shfl_xor(v, 1, 64));
  return v;
}

__device__ __forceinline__ void gld16(const void* g, void* l) {
  __builtin_amdgcn_global_load_lds((const __attribute__((address_space(1))) void*)g,
                                   (__attribute__((address_space(3))) void*)l, 16, 0, 0);
}

// ---------- K1: rowsum -> r[i] = rowsum^-0.5 ----------
__global__ __launch_bounds__(256) void k_rowsum(const float* __restrict__ adj, float* __restrict__ rr) {
  int i = blockIdx.x, t = threadIdx.x;
  const float4* row = (const float4*)(adj + (size_t)i * N_);
  float s = 0.f;
#pragma unroll
  for (int q = 0; q < 8; ++q) { float4 v = row[q * 256 + t]; s += (v.x + v.y) + (v.z + v.w); }
  s = wave_sum(s);
  __shared__ float part[4];
  if ((t & 63) == 0) part[t >> 6] = s;
  __syncthreads();
  if (t == 0) {
    float tot = (part[0] + part[1]) + (part[2] + part[3]);
    rr[i] = tot > 0.f ? 1.f / sqrtf(tot) : 0.f;
  }
}

// ---------- K2: adjT[i][j] = bf16(adj[j][i]) ----------
__global__ __launch_bounds__(256) void k_transpose(const float* __restrict__ adj, u16* __restrict__ adjT) {
  __shared__ float tile[64][65];
  int bi = blockIdx.x & 127, bj = blockIdx.x >> 7;
  int i0 = bi * 64, j0 = bj * 64;
  int t = threadIdx.x;
#pragma unroll
  for (int q = 0; q < 4; ++q) {
    int idx = q * 256 + t; int jl = idx >> 4, c4 = idx & 15;
    float4 v = *(const float4*)(adj + (size_t)(j0 + jl) * N_ + i0 + c4 * 4);
    tile[jl][c4 * 4 + 0] = v.x; tile[jl][c4 * 4 + 1] = v.y;
    tile[jl][c4 * 4 + 2] = v.z; tile[jl][c4 * 4 + 3] = v.w;
  }
  __syncthreads();
#pragma unroll
  for (int q = 0; q < 4; ++q) {
    int idx = q * 256 + t; int il = idx >> 4, c4 = idx & 15;
    u16x4 o;
    o.x = f2bf(tile[c4 * 4 + 0][il]); o.y = f2bf(tile[c4 * 4 + 1][il]);
    o.z = f2bf(tile[c4 * 4 + 2][il]); o.w = f2bf(tile[c4 * 4 + 3][il]);
    *(u16x4*)(adjT + (size_t)(i0 + il) * N_ + j0 + c4 * 4) = o;
  }
}

// ---------- K3: xt[b*64+d][j] = bf16(x[b][j][d] * r[j]) ----------
__global__ __launch_bounds__(256) void k_xt(const float* __restrict__ x, const float* __restrict__ rr,
                                            u16* __restrict__ xt) {
  __shared__ float tile[64][65];
  int b = blockIdx.x >> 7, j0 = (blockIdx.x & 127) * 64;
  int t = threadIdx.x;
#pragma unroll
  for (int q = 0; q < 4; ++q) {
    int idx = q * 256 + t; int jl = idx >> 4, c4 = idx & 15;
    float4 v = *(const float4*)(x + ((size_t)b * N_ + j0 + jl) * D_ + c4 * 4);
    float rv = rr[j0 + jl];
    tile[jl][c4 * 4 + 0] = v.x * rv; tile[jl][c4 * 4 + 1] = v.y * rv;
    tile[jl][c4 * 4 + 2] = v.z * rv; tile[jl][c4 * 4 + 3] = v.w * rv;
  }
  __syncthreads();
#pragma unroll
  for (int q = 0; q < 4; ++q) {
    int idx = q * 256 + t; int dl = idx >> 4, c4 = idx & 15;
    u16x4 o;
    o.x = f2bf(tile[c4 * 4 + 0][dl]); o.y = f2bf(tile[c4 * 4 + 1][dl]);
    o.z = f2bf(tile[c4 * 4 + 2][dl]); o.w = f2bf(tile[c4 * 4 + 3][dl]);
    *(u16x4*)(xt + (size_t)(b * 64 + dl) * N_ + j0 + c4 * 4) = o;
  }
}

// ---------- GEMM: C[m][n] = sum_k A[m][k]*B[n][k]  (both bf16, K-contiguous) ----------
template<int BM, int BN>
__global__ __launch_bounds__(256) void k_gemm(const u16* __restrict__ A, const u16* __restrict__ B,
                                              float* __restrict__ C, int N, int K) {
  constexpr int BK = 32;
  __shared__ __align__(16) u16 As[BM * BK];
  __shared__ __align__(16) u16 Bs[BN * BK];
  const int tid = threadIdx.x;
  const int nb = N / BN;
  const int bm = blockIdx.x / nb, bn = blockIdx.x % nb;
  const int m0 = bm * BM, n0 = bn * BN;
  constexpr int WM = BM / 2, WN = BN / 2;
  constexpr int FM = WM / 16, FN = WN / 16;
  const int wave = tid >> 6, lane = tid & 63;
  const int wm = (wave >> 1) * WM, wn = (wave & 1) * WN;
  const int lr = lane & 15, lk = lane >> 4;

  f32x4 acc[FM][FN];
#pragma unroll
  for (int a = 0; a < FM; ++a)
#pragma unroll
    for (int b = 0; b < FN; ++b) acc[a][b] = (f32x4){0.f, 0.f, 0.f, 0.f};

  for (int k0 = 0; k0 < K; k0 += BK) {
#pragma unroll
    for (int it = 0; it < BM / 64; ++it) {
      int c = it * 256 + tid;
      gld16(A + (size_t)(m0 + (c >> 2)) * K + k0 + (c & 3) * 8,
            As + ((size_t)it * 256 + (tid & 192)) * 8);
    }
#pragma unroll
    for (int it = 0; it < BN / 64; ++it) {
      int c = it * 256 + tid;
      gld16(B + (size_t)(n0 + (c >> 2)) * K + k0 + (c & 3) * 8,
            Bs + ((size_t)it * 256 + (tid & 192)) * 8);
    }
    __syncthreads();
    bf16x8 av[FM], bv[FN];
#pragma unroll
    for (int f = 0; f < FM; ++f)
      av[f] = *(const bf16x8*)(As + (wm + f * 16 + lr) * BK + lk * 8);
#pragma unroll
    for (int f = 0; f < FN; ++f)
      bv[f] = *(const bf16x8*)(Bs + (wn + f * 16 + lr) * BK + lk * 8);
#pragma unroll
    for (int fm = 0; fm < FM; ++fm)
#pragma unroll
      for (int fn = 0; fn < FN; ++fn)
        acc[fm][fn] = __builtin_amdgcn_mfma_f32_16x16x32_bf16(av[fm], bv[fn], acc[fm][fn], 0, 0, 0);
    __syncthreads();
  }
#pragma unroll
  for (int fm = 0; fm < FM; ++fm) {
    int row0 = m0 + wm + fm * 16 + lk * 4;
#pragma unroll
    for (int fn = 0; fn < FN; ++fn) {
      int col = n0 + wn + fn * 16 + lr;
#pragma unroll
      for (int p = 0; p < 4; ++p)
        C[(size_t)(row0 + p) * N + col] = acc[fm][fn][p];
    }
  }
}

// ---------- epi1: y=r[i]*T1+x ; z=y@W1+b1 ; L2norm(h) ; relu ; BN(node) ; write g1 ----------
__global__ __launch_bounds__(256) void k_epi1(const float* __restrict__ T1, const float* __restrict__ x,
    const float* __restrict__ rr, const float* __restrict__ W1, const float* __restrict__ b1,
    float* __restrict__ g1n, u16* __restrict__ g1t) {
  __shared__ __align__(16) float W1s[D_ * H_];   // 32 KB
  __shared__ float ys[256];
  __shared__ float red[8];
  __shared__ float nrm[4];
  __shared__ float st[2];
  int i = blockIdx.x, t = threadIdx.x;
#pragma unroll
  for (int q = 0; q < 8; ++q) ((float4*)W1s)[q * 256 + t] = ((const float4*)W1)[q * 256 + t];
  float rv = rr[i];
  {
    int b = t >> 6, d = t & 63;
    ys[t] = rv * T1[(size_t)i * 256 + t] + x[((size_t)b * N_ + i) * D_ + d];
  }
  __syncthreads();
  int h = t & 127, ba = t >> 7, bb = 2 + ba;
  float za = b1[h], zb = za;
#pragma unroll 8
  for (int d = 0; d < 64; ++d) {
    float w = W1s[d * H_ + h];
    za += ys[ba * 64 + d] * w;
    zb += ys[bb * 64 + d] * w;
  }
  int wave = t >> 6, lane = t & 63;
  float sa = wave_sum(za * za), sb = wave_sum(zb * zb);
  if (lane == 0) { red[wave] = sa; red[4 + wave] = sb; }
  __syncthreads();
  if (t == 0) {
    nrm[0] = fmaxf(sqrtf(red[0] + red[1]), 1e-12f);
    nrm[1] = fmaxf(sqrtf(red[2] + red[3]), 1e-12f);
    nrm[2] = fmaxf(sqrtf(red[4] + red[5]), 1e-12f);
    nrm[3] = fmaxf(sqrtf(red[6] + red[7]), 1e-12f);
  }
  __syncthreads();
  za = fmaxf(za / nrm[ba], 0.f);
  zb = fmaxf(zb / nrm[bb], 0.f);
  float s1 = wave_sum(za + zb), s2 = wave_sum(za * za + zb * zb);
  if (lane == 0) { red[wave] = s1; red[4 + wave] = s2; }
  __syncthreads();
  if (t == 0) {
    float m = (red[0] + red[1] + red[2] + red[3]) * (1.f / 512.f);
    float e2 = (red[4] + red[5] + red[6] + red[7]) * (1.f / 512.f);
    st[0] = m; st[1] = 1.f / sqrtf(e2 - m * m + 1e-5f);
  }
  __syncthreads();
  float ga = (za - st[0]) * st[1], gb = (zb - st[0]) * st[1];
  g1n[(size_t)i * 512 + t] = ga;
  g1n[(size_t)i * 512 + 256 + t] = gb;
  g1t[(size_t)t * N_ + i] = f2bf(ga * rv);
  g1t[(size_t)(256 + t) * N_ + i] = f2bf(gb * rv);
}

// ---------- epi2: y=r[i]*T2+g1 ; z=y@W2+b2 ; L2norm(e) ; relu ; BN(node) ; write g2 ----------
__global__ __launch_bounds__(256) void k_epi2(const float* __restrict__ T2, const float* __restrict__ g1n,
    const float* __restrict__ rr, const float* __restrict__ W2, const float* __restrict__ b2,
    float* __restrict__ g2n) {
  __shared__ __align__(16) float ysm[8 * 512];     // 16 KB, c' = b*128+h
  __shared__ __align__(16) float W2s[32 * 256];    // 32 KB chunk of W2
  __shared__ float red1[128];
  __shared__ float nv[32];
  __shared__ float redA[32], redB[32];
  __shared__ float mn[8], iv[8];
  int i0 = blockIdx.x * 8, t = threadIdx.x;
#pragma unroll
  for (int q = 0; q < 4; ++q) {
    int idx = q * 256 + t; int n = idx >> 7, c4 = idx & 127;
    int i = i0 + n;
    float rv = rr[i];
    float4 a = *(const float4*)(T2 + (size_t)i * 512 + c4 * 4);
    float4 g = *(const float4*)(g1n + (size_t)i * 512 + c4 * 4);
    float4 y;
    y.x = rv * a.x + g.x; y.y = rv * a.y + g.y; y.z = rv * a.z + g.z; y.w = rv * a.w + g.w;
    *(float4*)&ysm[n * 512 + c4 * 4] = y;
  }
  int e = t;
  float z[8][4];
#pragma unroll
  for (int n = 0; n < 8; ++n)
#pragma unroll
    for (int b = 0; b < 4; ++b) z[n][b] = 0.f;

  for (int hc = 0; hc < H_; hc += 32) {
    __syncthreads();
#pragma unroll
    for (int q = 0; q < 8; ++q) {
      int idx = q * 256 + t;
      ((float4*)W2s)[idx] = ((const float4*)(W2 + (size_t)hc * 256))[idx];
    }
    __syncthreads();
#pragma unroll
    for (int h4 = 0; h4 < 32; h4 += 4) {
      float w0 = W2s[(h4 + 0) * 256 + e];
      float w1 = W2s[(h4 + 1) * 256 + e];
      float w2 = W2s[(h4 + 2) * 256 + e];
      float w3 = W2s[(h4 + 3) * 256 + e];
#pragma unroll
      for (int n = 0; n < 8; ++n) {
#pragma unroll
        for (int b = 0; b < 4; ++b) {
          float4 y = *(const float4*)&ysm[n * 512 + b * 128 + hc + h4];
          z[n][b] += y.x * w0 + y.y * w1 + y.z * w2 + y.w * w3;
        }
      }
    }
  }
  float b2e = b2[e];
  int wave = t >> 6, lane = t & 63;
#pragma unroll
  for (int n = 0; n < 8; ++n)
#pragma unroll
    for (int b = 0; b < 4; ++b) {
      z[n][b] += b2e;
      float s = wave_sum(z[n][b] * z[n][b]);
      if (lane == 0) red1[n * 16 + b * 4 + wave] = s;
    }
  __syncthreads();
  if (t < 32) {
    float s = red1[t * 4 + 0] + red1[t * 4 + 1] + red1[t * 4 + 2] + red1[t * 4 + 3];
    nv[t] = fmaxf(sqrtf(s), 1e-12f);
  }
  __syncthreads();
#pragma unroll
  for (int n = 0; n < 8; ++n) {
    float s1 = 0.f, s2 = 0.f;
#pragma unroll
    for (int b = 0; b < 4; ++b) {
      z[n][b] = fmaxf(z[n][b] / nv[n * 4 + b], 0.f);
      s1 += z[n][b]; s2 += z[n][b] * z[n][b];
    }
    s1 = wave_sum(s1); s2 = wave_sum(s2);
    if (lane == 0) { redA[n * 4 + wave] = s1; redB[n * 4 + wave] = s2; }
  }
  __syncthreads();
  if (t < 8) {
    float s1 = redA[t * 4] + redA[t * 4 + 1] + redA[t * 4 + 2] + redA[t * 4 + 3];
    float s2 = redB[t * 4] + redB[t * 4 + 1] + redB[t * 4 + 2] + redB[t * 4 + 3];
    float m = s1 * (1.f / 1024.f), v = s2 * (1.f / 1024.f) - m * m;
    mn[t] = m; iv[t] = 1.f / sqrtf(v + 1e-5f);
  }
  __syncthreads();
#pragma unroll
  for (int n = 0; n < 8; ++n)
#pragma unroll
    for (int b = 0; b < 4; ++b)
      g2n[(size_t)(i0 + n) * 1024 + b * 256 + e] = (z[n][b] - mn[n]) * iv[n];
}

// ---------- pred: pred[b][n][c] = g2 @ Wp + bp ----------
__global__ __launch_bounds__(256) void k_pred(const float* __restrict__ g2n, const float* __restrict__ Wp,
    const float* __restrict__ bp, float* __restrict__ pred) {
  __shared__ __align__(16) float gs[8 * 1028];    // pad rows to 1028
  __shared__ __align__(16) float Wps[E_ * C_];    // 16 KB
  int i0 = blockIdx.x * 8, t = threadIdx.x;
#pragma unroll
  for (int q = 0; q < 4; ++q) ((float4*)Wps)[q * 256 + t] = ((const float4*)Wp)[q * 256 + t];
#pragma unroll
  for (int q = 0; q < 8; ++q) {
    int idx = q * 256 + t; int n = idx >> 8, c4 = idx & 255;
    *(float4*)&gs[n * 1028 + c4 * 4] = *(const float4*)(g2n + (size_t)(i0 + n) * 1024 + c4 * 4);
  }
  __syncthreads();
#pragma unroll
  for (int s = 0; s < 2; ++s) {
    int o = s * 256 + t; int n = o >> 6, b = (o >> 4) & 3, c = o & 15;
    float acc = bp[c];
    const float* g = &gs[n * 1028 + b * 256];
#pragma unroll 16
    for (int e2 = 0; e2 < 256; e2 += 4) {
      float4 gv = *(const float4*)&g[e2];
      acc += gv.x * Wps[(e2 + 0) * 16 + c] + gv.y * Wps[(e2 + 1) * 16 + c]
           + gv.z * Wps[(e2 + 2) * 16 + c] + gv.w * Wps[(e2 + 3) * 16 + c];
    }
    pred[((size_t)b * N_ + i0 + n) * C_ + c] = acc;
  }
}

// ---------- softmax over node axis, per (b, c) ----------
__global__ __launch_bounds__(256) void k_softmax(const float* __restrict__ pred, float* __restrict__ out) {
  int b = blockIdx.x >> 4, c = blockIdx.x & 15, t = threadIdx.x;
  const float* p = pred + (size_t)b * N_ * C_ + c;
  float* po = out + (size_t)b * N_ * C_ + c;
  float v[32];
  float mx = -3.4e38f;
#pragma unroll
  for (int k = 0; k < 32; ++k) { v[k] = p[(size_t)(t + 256 * k) * C_]; mx = fmaxf(mx, v[k]); }
  mx = wave_max(mx);
  __shared__ float pm[4];
  __shared__ float ps[4];
  int wave = t >> 6, lane = t & 63;
  if (lane == 0) pm[wave] = mx;
  __syncthreads();
  mx = fmaxf(fmaxf(pm[0], pm[1]), fmaxf(pm[2], pm[3]));
  float s = 0.f;
#pragma unroll
  for (int k = 0; k < 32; ++k) { v[k] = __expf(v[k] - mx); s += v[k]; }
  s = wave_sum(s);
  if (lane == 0) ps[wave] = s;
  __syncthreads();
  s = (ps[0] + ps[1]) + (ps[2] + ps[3]);
  float inv = 1.f / s;
#pragma unroll
  for (int k = 0; k < 32; ++k) po[(size_t)(t + 256 * k) * C_] = v[k] * inv;
}

extern "C" void kernel_launch(void* const* d_in, const int* in_sizes, int n_in,
                              void* d_out, int out_size, void* d_ws, size_t ws_size,
                              hipStream_t stream) {
  const float* x   = (const float*)d_in[0];
  const float* adj = (const float*)d_in[1];
  const float* W1  = (const float*)d_in[2];
  const float* b1  = (const float*)d_in[3];
  const float* W2  = (const float*)d_in[4];
  const float* b2  = (const float*)d_in[5];
  const float* Wp  = (const float*)d_in[6];
  const float* bp  = (const float*)d_in[7];
  float* out = (float*)d_out;
  char* ws = (char*)d_ws;

  size_t o = 0;
  u16*   adjT = (u16*)(ws + o);   o += (size_t)N_ * N_ * 2;        // 128 MB
  float* rr   = (float*)(ws + o); o += (size_t)N_ * 4;             // 32 KB
  u16*   xt   = (u16*)(ws + o);   o += (size_t)256 * N_ * 2;       // 4 MB
  float* T1   = (float*)(ws + o); o += (size_t)N_ * 256 * 4;       // 8 MB
  u16*   g1t  = (u16*)(ws + o);   o += (size_t)512 * N_ * 2;       // 8 MB
  float* g1n  = (float*)(ws + o); o += (size_t)N_ * 512 * 4;       // 16 MB
  float* T2   = (float*)(ws + o); o += (size_t)N_ * 512 * 4;       // 16 MB
  // adjT region is dead after GEMM2 -> reuse for g2n and pred
  float* g2n  = (float*)ws;                                        // 32 MB
  float* pred = (float*)(ws + (size_t)33554432);                   // 2 MB

  k_rowsum   <<<N_, 256, 0, stream>>>(adj, rr);
  k_transpose<<<128 * 128, 256, 0, stream>>>(adj, adjT);
  k_xt       <<<4 * 128, 256, 0, stream>>>(x, rr, xt);
  k_gemm<128, 64><<<(N_ / 128) * (256 / 64), 256, 0, stream>>>(adjT, xt, T1, 256, N_);
  k_epi1     <<<N_, 256, 0, stream>>>(T1, x, rr, W1, b1, g1n, g1t);
  k_gemm<128, 128><<<(N_ / 128) * (512 / 128), 256, 0, stream>>>(adjT, g1t, T2, 512, N_);
  k_epi2     <<<N_ / 8, 256, 0, stream>>>(T2, g1n, rr, W2, b2, g2n);
  k_pred     <<<N_ / 8, 256, 0, stream>>>(g2n, Wp, bp, pred);
  k_softmax  <<<64, 256, 0, stream>>>(pred, out);
}

// Round 2
// 847.135 us; speedup vs baseline: 1.1860x; 1.1860x over previous
//
#include <hip/hip_runtime.h>
#include <hip/hip_bf16.h>
#include <cstdint>
#include <cstddef>

typedef unsigned short u16;
typedef __attribute__((ext_vector_type(8))) short bf16x8;   // MFMA A/B frag (8 bf16)
typedef __attribute__((ext_vector_type(4))) float f32x4;    // MFMA C/D frag
typedef __attribute__((ext_vector_type(4))) unsigned short u16x4;

#define B_ 4
#define N_ 8192
#define D_ 64
#define H_ 128
#define E_ 256
#define C_ 16

// ---------- helpers ----------
__device__ __forceinline__ u16 f2bf(float f) {
  unsigned u = __builtin_bit_cast(unsigned, f);
  u += 0x7fffu + ((u >> 16) & 1u);          // RNE
  return (u16)(u >> 16);
}
__device__ __forceinline__ float bf2f(u16 u) {
  return __builtin_bit_cast(float, ((unsigned)u) << 16);
}

__device__ __forceinline__ float wave_sum(float v) {
  v += __shfl_xor(v, 32, 64); v += __shfl_xor(v, 16, 64); v += __shfl_xor(v, 8, 64);
  v += __shfl_xor(v, 4, 64);  v += __shfl_xor(v, 2, 64);  v += __shfl_xor(v, 1, 64);
  return v;
}
__device__ __forceinline__ float wave_max(float v) {
  v = fmaxf(v, __shfl_xor(v, 32, 64)); v = fmaxf(v, __shfl_xor(v, 16, 64));
  v = fmaxf(v, __shfl_xor(v, 8, 64));  v = fmaxf(v, __shfl_xor(v, 4, 64));
  v = fmaxf(v, __shfl_xor(v, 2, 64));  v = fmaxf(v, __shfl_xor(v, 1, 64));
  return v;
}

__device__ __forceinline__ void gld16(const void* g, void* l) {
  __builtin_amdgcn_global_load_lds((const __attribute__((address_space(1))) void*)g,
                                   (__attribute__((address_space(3))) void*)l, 16, 0, 0);
}

// ---------- zero init (for atomic rowsum) ----------
__global__ __launch_bounds__(256) void k_zero(float* __restrict__ p, int n) {
  int i = blockIdx.x * 256 + threadIdx.x;
  if (i < n) p[i] = 0.f;
}

// ---------- transpose + fused rowsum: adjT[i][j]=bf16(adj[j][i]); rsum[j]+=partial ----------
__global__ __launch_bounds__(256) void k_transpose(const float* __restrict__ adj, u16* __restrict__ adjT,
                                                   float* __restrict__ rsum) {
  __shared__ float tile[64][65];
  int bi = blockIdx.x & 127, bj = blockIdx.x >> 7;
  int i0 = bi * 64, j0 = bj * 64;
  int t = threadIdx.x;
#pragma unroll
  for (int q = 0; q < 4; ++q) {
    int idx = q * 256 + t; int jl = idx >> 4, c4 = idx & 15;
    float4 v = *(const float4*)(adj + (size_t)(j0 + jl) * N_ + i0 + c4 * 4);
    tile[jl][c4 * 4 + 0] = v.x; tile[jl][c4 * 4 + 1] = v.y;
    tile[jl][c4 * 4 + 2] = v.z; tile[jl][c4 * 4 + 3] = v.w;
    float s = (v.x + v.y) + (v.z + v.w);
    s += __shfl_xor(s, 1, 64); s += __shfl_xor(s, 2, 64);
    s += __shfl_xor(s, 4, 64); s += __shfl_xor(s, 8, 64);
    if ((t & 15) == 0) atomicAdd(&rsum[j0 + jl], s);
  }
  __syncthreads();
#pragma unroll
  for (int q = 0; q < 4; ++q) {
    int idx = q * 256 + t; int il = idx >> 4, c4 = idx & 15;
    u16x4 o;
    o.x = f2bf(tile[c4 * 4 + 0][il]); o.y = f2bf(tile[c4 * 4 + 1][il]);
    o.z = f2bf(tile[c4 * 4 + 2][il]); o.w = f2bf(tile[c4 * 4 + 3][il]);
    *(u16x4*)(adjT + (size_t)(i0 + il) * N_ + j0 + c4 * 4) = o;
  }
}

// ---------- rsum -> rr = rsum^-0.5 ----------
__global__ __launch_bounds__(256) void k_rsqrt(const float* __restrict__ rsum, float* __restrict__ rr) {
  int i = blockIdx.x * 256 + threadIdx.x;
  float s = rsum[i];
  rr[i] = s > 0.f ? rsqrtf(s) : 0.f;
}

// ---------- xt[b*64+d][j] = bf16(x[b][j][d] * r[j]) ----------
__global__ __launch_bounds__(256) void k_xt(const float* __restrict__ x, const float* __restrict__ rr,
                                            u16* __restrict__ xt) {
  __shared__ float tile[64][65];
  int b = blockIdx.x >> 7, j0 = (blockIdx.x & 127) * 64;
  int t = threadIdx.x;
#pragma unroll
  for (int q = 0; q < 4; ++q) {
    int idx = q * 256 + t; int jl = idx >> 4, c4 = idx & 15;
    float4 v = *(const float4*)(x + ((size_t)b * N_ + j0 + jl) * D_ + c4 * 4);
    float rv = rr[j0 + jl];
    tile[jl][c4 * 4 + 0] = v.x * rv; tile[jl][c4 * 4 + 1] = v.y * rv;
    tile[jl][c4 * 4 + 2] = v.z * rv; tile[jl][c4 * 4 + 3] = v.w * rv;
  }
  __syncthreads();
#pragma unroll
  for (int q = 0; q < 4; ++q) {
    int idx = q * 256 + t; int dl = idx >> 4, c4 = idx & 15;
    u16x4 o;
    o.x = f2bf(tile[c4 * 4 + 0][dl]); o.y = f2bf(tile[c4 * 4 + 1][dl]);
    o.z = f2bf(tile[c4 * 4 + 2][dl]); o.w = f2bf(tile[c4 * 4 + 3][dl]);
    *(u16x4*)(xt + (size_t)(b * 64 + dl) * N_ + j0 + c4 * 4) = o;
  }
}

// ---------- split-K GEMM: Cp[ks][m][n] = bf16( sum_{k in slice} A[m][k]*B[n][k] ) ----------
template<int BM, int BN, int KS>
__global__ __launch_bounds__(256) void k_gemm(const u16* __restrict__ A, const u16* __restrict__ B,
                                              u16* __restrict__ Cp, int N) {
  constexpr int BK = 32;
  __shared__ __align__(16) u16 As[BM * BK];
  __shared__ __align__(16) u16 Bs[BN * BK];
  const int tid = threadIdx.x;
  const int nb = N / BN;
  const int bn = blockIdx.x % nb;
  const int kb = (blockIdx.x / nb) % KS;
  const int bm = blockIdx.x / (nb * KS);
  const int m0 = bm * BM, n0 = bn * BN;
  const int kbeg = kb * (N_ / KS), kend = kbeg + N_ / KS;
  constexpr int WM = BM / 2, WN = BN / 2;
  constexpr int FM = WM / 16, FN = WN / 16;
  const int wave = tid >> 6, lane = tid & 63;
  const int wm = (wave >> 1) * WM, wn = (wave & 1) * WN;
  const int lr = lane & 15, lk = lane >> 4;

  f32x4 acc[FM][FN];
#pragma unroll
  for (int a = 0; a < FM; ++a)
#pragma unroll
    for (int b = 0; b < FN; ++b) acc[a][b] = (f32x4){0.f, 0.f, 0.f, 0.f};

  for (int k0 = kbeg; k0 < kend; k0 += BK) {
#pragma unroll
    for (int it = 0; it < BM / 64; ++it) {
      int c = it * 256 + tid;
      gld16(A + (size_t)(m0 + (c >> 2)) * N_ + k0 + (c & 3) * 8,
            As + ((size_t)it * 256 + (tid & 192)) * 8);
    }
#pragma unroll
    for (int it = 0; it < BN / 64; ++it) {
      int c = it * 256 + tid;
      gld16(B + (size_t)(n0 + (c >> 2)) * N_ + k0 + (c & 3) * 8,
            Bs + ((size_t)it * 256 + (tid & 192)) * 8);
    }
    __syncthreads();
    bf16x8 av[FM], bv[FN];
#pragma unroll
    for (int f = 0; f < FM; ++f)
      av[f] = *(const bf16x8*)(As + (wm + f * 16 + lr) * BK + lk * 8);
#pragma unroll
    for (int f = 0; f < FN; ++f)
      bv[f] = *(const bf16x8*)(Bs + (wn + f * 16 + lr) * BK + lk * 8);
#pragma unroll
    for (int fm = 0; fm < FM; ++fm)
#pragma unroll
      for (int fn = 0; fn < FN; ++fn)
        acc[fm][fn] = __builtin_amdgcn_mfma_f32_16x16x32_bf16(av[fm], bv[fn], acc[fm][fn], 0, 0, 0);
    __syncthreads();
  }
  u16* Cs = Cp + (size_t)kb * N_ * N;
#pragma unroll
  for (int fm = 0; fm < FM; ++fm) {
    int row0 = m0 + wm + fm * 16 + lk * 4;
#pragma unroll
    for (int fn = 0; fn < FN; ++fn) {
      int col = n0 + wn + fn * 16 + lr;
#pragma unroll
      for (int p = 0; p < 4; ++p)
        Cs[(size_t)(row0 + p) * N + col] = f2bf(acc[fm][fn][p]);
    }
  }
}

// ---------- epi1: 16 nodes/block. y=r*sum(T1p)+x ; z=y@W1+b1 ; L2norm ; relu ; BN ; g1n,g1t ----------
__global__ __launch_bounds__(256) void k_epi1(const u16* __restrict__ T1p, const float* __restrict__ x,
    const float* __restrict__ rr, const float* __restrict__ W1, const float* __restrict__ b1,
    float* __restrict__ g1n, u16* __restrict__ g1t) {
  union SharedU { float ys[16][256]; u16 gb[512][18]; };
  __shared__ SharedU su;                 // max(16KB, 18KB)
  __shared__ float zbuf[16][512];        // 32 KB
  __shared__ float rs[16];
  const int t = threadIdx.x;
  const int i0 = blockIdx.x * 16;
  constexpr size_t SL = (size_t)N_ * 256;
  if (t < 16) rs[t] = rr[i0 + t];
  __syncthreads();
  // phase 0: ys[n][c] = r*sum_ks T1p + x   (c = b*64+d)
#pragma unroll
  for (int q = 0; q < 16; ++q) {
    int idx = q * 256 + t; int n = idx >> 8, c = idx & 255, b = c >> 6, d = c & 63;
    size_t ti = (size_t)(i0 + n) * 256 + c;
    float s = bf2f(T1p[ti]) + bf2f(T1p[ti + SL]) + bf2f(T1p[ti + 2 * SL]) + bf2f(T1p[ti + 3 * SL]);
    su.ys[n][c] = rs[n] * s + x[((size_t)b * N_ + i0 + n) * D_ + d];
  }
  // phase 1: W1 column into registers
  const int h = t & 127, bh = t >> 7;
  float w[64];
#pragma unroll
  for (int d = 0; d < 64; ++d) w[d] = W1[d * H_ + h];
  float b1h = b1[h];
  __syncthreads();
  // phase 2: z[n][c'] for c' = b*128+h
  for (int n = 0; n < 16; ++n) {
    float za = b1h, zb = b1h;
#pragma unroll
    for (int d = 0; d < 64; ++d) {
      za += su.ys[n][bh * 64 + d] * w[d];
      zb += su.ys[n][(bh + 2) * 64 + d] * w[d];
    }
    zbuf[n][bh * 128 + h] = za;
    zbuf[n][(bh + 2) * 128 + h] = zb;
  }
  __syncthreads();
  // phase 3: per-wave nodes, no barriers
  const int wv = t >> 6, lane = t & 63;
#pragma unroll
  for (int nn = 0; nn < 4; ++nn) {
    int n = wv * 4 + nn;
    float v[8], nb2[8];
#pragma unroll
    for (int q = 0; q < 8; ++q) { v[q] = zbuf[n][q * 64 + lane]; }
#pragma unroll
    for (int q = 0; q < 8; ++q) nb2[q] = wave_sum(v[q] * v[q]);
    float inv0 = 1.f / fmaxf(sqrtf(nb2[0] + nb2[1]), 1e-12f);
    float inv1 = 1.f / fmaxf(sqrtf(nb2[2] + nb2[3]), 1e-12f);
    float inv2 = 1.f / fmaxf(sqrtf(nb2[4] + nb2[5]), 1e-12f);
    float inv3 = 1.f / fmaxf(sqrtf(nb2[6] + nb2[7]), 1e-12f);
    float sc[4] = {inv0, inv1, inv2, inv3};
    float t1 = 0.f, t2 = 0.f;
#pragma unroll
    for (int q = 0; q < 8; ++q) {
      v[q] = fmaxf(v[q] * sc[q >> 1], 0.f);
      t1 += v[q]; t2 += v[q] * v[q];
    }
    float s1 = wave_sum(t1), s2 = wave_sum(t2);
    float m = s1 * (1.f / 512.f);
    float var = s2 * (1.f / 512.f) - m * m;
    float iv = rsqrtf(var + 1e-5f);
    float rv = rs[n];
#pragma unroll
    for (int q = 0; q < 8; ++q) {
      float g = (v[q] - m) * iv;
      g1n[(size_t)(i0 + n) * 512 + q * 64 + lane] = g;
      su.gb[q * 64 + lane][n] = f2bf(g * rv);
    }
  }
  __syncthreads();
  // phase 4: coalesced transposed write of g1t
#pragma unroll
  for (int rep = 0; rep < 2; ++rep) {
    int c = rep * 256 + t;
    const unsigned* src = (const unsigned*)&su.gb[c][0];
    uint4 o0, o1;
    o0.x = src[0]; o0.y = src[1]; o0.z = src[2]; o0.w = src[3];
    o1.x = src[4]; o1.y = src[5]; o1.z = src[6]; o1.w = src[7];
    uint4* dst = (uint4*)(g1t + (size_t)c * N_ + i0);
    dst[0] = o0; dst[1] = o1;
  }
}

// ---------- epi2: y=r*sum(T2p)+g1 ; z=y@W2+b2 ; L2norm(e) ; relu ; BN ; g2n ----------
__global__ __launch_bounds__(256) void k_epi2(const u16* __restrict__ T2p, const float* __restrict__ g1n,
    const float* __restrict__ rr, const float* __restrict__ W2, const float* __restrict__ b2,
    float* __restrict__ g2n) {
  __shared__ __align__(16) float ysm[8 * 512];     // 16 KB
  __shared__ __align__(16) float W2s[32 * 256];    // 32 KB
  __shared__ float red1[128];
  __shared__ float nv[32];
  __shared__ float redA[32], redB[32];
  __shared__ float mn[8], iv[8];
  constexpr size_t SL = (size_t)N_ * 512;
  int i0 = blockIdx.x * 8, t = threadIdx.x;
#pragma unroll
  for (int q = 0; q < 4; ++q) {
    int idx = q * 256 + t; int n = idx >> 7, c4 = idx & 127;
    int i = i0 + n;
    float rv = rr[i];
    size_t ti = (size_t)i * 512 + c4 * 4;
    u16x4 p0 = *(const u16x4*)(T2p + ti);
    u16x4 p1 = *(const u16x4*)(T2p + SL + ti);
    float4 g = *(const float4*)(g1n + ti);
    float4 y;
    y.x = rv * (bf2f(p0.x) + bf2f(p1.x)) + g.x;
    y.y = rv * (bf2f(p0.y) + bf2f(p1.y)) + g.y;
    y.z = rv * (bf2f(p0.z) + bf2f(p1.z)) + g.z;
    y.w = rv * (bf2f(p0.w) + bf2f(p1.w)) + g.w;
    *(float4*)&ysm[n * 512 + c4 * 4] = y;
  }
  int e = t;
  float z[8][4];
#pragma unroll
  for (int n = 0; n < 8; ++n)
#pragma unroll
    for (int b = 0; b < 4; ++b) z[n][b] = 0.f;

  for (int hc = 0; hc < H_; hc += 32) {
    __syncthreads();
#pragma unroll
    for (int q = 0; q < 8; ++q) {
      int idx = q * 256 + t;
      ((float4*)W2s)[idx] = ((const float4*)(W2 + (size_t)hc * 256))[idx];
    }
    __syncthreads();
#pragma unroll
    for (int h4 = 0; h4 < 32; h4 += 4) {
      float w0 = W2s[(h4 + 0) * 256 + e];
      float w1 = W2s[(h4 + 1) * 256 + e];
      float w2 = W2s[(h4 + 2) * 256 + e];
      float w3 = W2s[(h4 + 3) * 256 + e];
#pragma unroll
      for (int n = 0; n < 8; ++n) {
#pragma unroll
        for (int b = 0; b < 4; ++b) {
          float4 y = *(const float4*)&ysm[n * 512 + b * 128 + hc + h4];
          z[n][b] += y.x * w0 + y.y * w1 + y.z * w2 + y.w * w3;
        }
      }
    }
  }
  float b2e = b2[e];
  int wave = t >> 6, lane = t & 63;
#pragma unroll
  for (int n = 0; n < 8; ++n)
#pragma unroll
    for (int b = 0; b < 4; ++b) {
      z[n][b] += b2e;
      float s = wave_sum(z[n][b] * z[n][b]);
      if (lane == 0) red1[n * 16 + b * 4 + wave] = s;
    }
  __syncthreads();
  if (t < 32) {
    float s = red1[t * 4 + 0] + red1[t * 4 + 1] + red1[t * 4 + 2] + red1[t * 4 + 3];
    nv[t] = fmaxf(sqrtf(s), 1e-12f);
  }
  __syncthreads();
#pragma unroll
  for (int n = 0; n < 8; ++n) {
    float s1 = 0.f, s2 = 0.f;
#pragma unroll
    for (int b = 0; b < 4; ++b) {
      z[n][b] = fmaxf(z[n][b] / nv[n * 4 + b], 0.f);
      s1 += z[n][b]; s2 += z[n][b] * z[n][b];
    }
    s1 = wave_sum(s1); s2 = wave_sum(s2);
    if (lane == 0) { redA[n * 4 + wave] = s1; redB[n * 4 + wave] = s2; }
  }
  __syncthreads();
  if (t < 8) {
    float s1 = redA[t * 4] + redA[t * 4 + 1] + redA[t * 4 + 2] + redA[t * 4 + 3];
    float s2 = redB[t * 4] + redB[t * 4 + 1] + redB[t * 4 + 2] + redB[t * 4 + 3];
    float m = s1 * (1.f / 1024.f), v = s2 * (1.f / 1024.f) - m * m;
    mn[t] = m; iv[t] = 1.f / sqrtf(v + 1e-5f);
  }
  __syncthreads();
#pragma unroll
  for (int n = 0; n < 8; ++n)
#pragma unroll
    for (int b = 0; b < 4; ++b)
      g2n[(size_t)(i0 + n) * 1024 + b * 256 + e] = (z[n][b] - mn[n]) * iv[n];
}

// ---------- pred ----------
__global__ __launch_bounds__(256) void k_pred(const float* __restrict__ g2n, const float* __restrict__ Wp,
    const float* __restrict__ bp, float* __restrict__ pred) {
  __shared__ __align__(16) float gs[8 * 1028];
  __shared__ __align__(16) float Wps[E_ * C_];
  int i0 = blockIdx.x * 8, t = threadIdx.x;
#pragma unroll
  for (int q = 0; q < 4; ++q) ((float4*)Wps)[q * 256 + t] = ((const float4*)Wp)[q * 256 + t];
#pragma unroll
  for (int q = 0; q < 8; ++q) {
    int idx = q * 256 + t; int n = idx >> 8, c4 = idx & 255;
    *(float4*)&gs[n * 1028 + c4 * 4] = *(const float4*)(g2n + (size_t)(i0 + n) * 1024 + c4 * 4);
  }
  __syncthreads();
#pragma unroll
  for (int s = 0; s < 2; ++s) {
    int o = s * 256 + t; int n = o >> 6, b = (o >> 4) & 3, c = o & 15;
    float acc = bp[c];
    const float* g = &gs[n * 1028 + b * 256];
#pragma unroll 16
    for (int e2 = 0; e2 < 256; e2 += 4) {
      float4 gv = *(const float4*)&g[e2];
      acc += gv.x * Wps[(e2 + 0) * 16 + c] + gv.y * Wps[(e2 + 1) * 16 + c]
           + gv.z * Wps[(e2 + 2) * 16 + c] + gv.w * Wps[(e2 + 3) * 16 + c];
    }
    pred[((size_t)b * N_ + i0 + n) * C_ + c] = acc;
  }
}

// ---------- softmax over node axis ----------
__global__ __launch_bounds__(256) void k_softmax(const float* __restrict__ pred, float* __restrict__ out) {
  int b = blockIdx.x >> 4, c = blockIdx.x & 15, t = threadIdx.x;
  const float* p = pred + (size_t)b * N_ * C_ + c;
  float* po = out + (size_t)b * N_ * C_ + c;
  float v[32];
  float mx = -3.4e38f;
#pragma unroll
  for (int k = 0; k < 32; ++k) { v[k] = p[(size_t)(t + 256 * k) * C_]; mx = fmaxf(mx, v[k]); }
  mx = wave_max(mx);
  __shared__ float pm[4];
  __shared__ float ps[4];
  int wave = t >> 6, lane = t & 63;
  if (lane == 0) pm[wave] = mx;
  __syncthreads();
  mx = fmaxf(fmaxf(pm[0], pm[1]), fmaxf(pm[2], pm[3]));
  float s = 0.f;
#pragma unroll
  for (int k = 0; k < 32; ++k) { v[k] = __expf(v[k] - mx); s += v[k]; }
  s = wave_sum(s);
  if (lane == 0) ps[wave] = s;
  __syncthreads();
  s = (ps[0] + ps[1]) + (ps[2] + ps[3]);
  float inv = 1.f / s;
#pragma unroll
  for (int k = 0; k < 32; ++k) po[(size_t)(t + 256 * k) * C_] = v[k] * inv;
}

extern "C" void kernel_launch(void* const* d_in, const int* in_sizes, int n_in,
                              void* d_out, int out_size, void* d_ws, size_t ws_size,
                              hipStream_t stream) {
  const float* x   = (const float*)d_in[0];
  const float* adj = (const float*)d_in[1];
  const float* W1  = (const float*)d_in[2];
  const float* b1  = (const float*)d_in[3];
  const float* W2  = (const float*)d_in[4];
  const float* b2  = (const float*)d_in[5];
  const float* Wp  = (const float*)d_in[6];
  const float* bp  = (const float*)d_in[7];
  float* out = (float*)d_out;
  char* ws = (char*)d_ws;

  // layout (peak 180.4 MB, <= 188.8 MB proven in round 0)
  size_t o = 0;
  u16*   adjT = (u16*)(ws + o);   o += (size_t)N_ * N_ * 2;        // 128 MB
  float* rsum = (float*)(ws + o); o += (size_t)N_ * 4;             // 32 KB
  float* rr   = (float*)(ws + o); o += (size_t)N_ * 4;             // 32 KB
  float* g1n  = (float*)(ws + o); o += (size_t)N_ * 512 * 4;       // 16 MB
  u16*   g1t  = (u16*)(ws + o);   o += (size_t)512 * N_ * 2;       // 8 MB
  size_t xoff = o;
  u16*   xt   = (u16*)(ws + xoff);                                  // 4 MB
  u16*   T1p  = (u16*)(ws + xoff + (size_t)256 * N_ * 2);           // 16 MB (4 slices bf16)
  u16*   T2p  = (u16*)(ws + xoff);                                  // 16 MB (2 slices bf16), reuses xt+T1p
  // adjT region dead after GEMM2:
  float* g2n  = (float*)ws;                                         // 32 MB
  float* pred = (float*)(ws + (size_t)33554432);                    // 2 MB

  k_zero     <<<N_ / 256, 256, 0, stream>>>(rsum, N_);
  k_transpose<<<128 * 128, 256, 0, stream>>>(adj, adjT, rsum);
  k_rsqrt    <<<N_ / 256, 256, 0, stream>>>(rsum, rr);
  k_xt       <<<4 * 128, 256, 0, stream>>>(x, rr, xt);
  k_gemm<128, 64, 4><<<(N_ / 128) * (256 / 64) * 4, 256, 0, stream>>>(adjT, xt, T1p, 256);
  k_epi1     <<<N_ / 16, 256, 0, stream>>>(T1p, x, rr, W1, b1, g1n, g1t);
  k_gemm<128, 64, 2><<<(N_ / 128) * (512 / 64) * 2, 256, 0, stream>>>(adjT, g1t, T2p, 512);
  k_epi2     <<<N_ / 8, 256, 0, stream>>>(T2p, g1n, rr, W2, b2, g2n);
  k_pred     <<<N_ / 8, 256, 0, stream>>>(g2n, Wp, bp, pred);
  k_softmax  <<<64, 256, 0, stream>>>(pred, out);
}